// Round 4
// baseline (346.045 us; speedup 1.0000x reference)
//
#include <hip/hip_runtime.h>

// UpdateFunction: GRU-ish gated node update, B=64, N=1024, D=256.
//   z = sigmoid(m@w_z + h@u_z); r = sigmoid(m@w_r + h@u_r)
//   htil = tanh(m@w + (r*h)@u); out = mask * ((1-z)*h + z*htil)
// bf16 MFMA 16x16x32, fragment-major pre-packed weights (1KB coalesced B-loads).
// R6: ROWS 32->64 halved weight re-fetch (2.3->1.15GB): 239->166us. Confirmed
//     weight-L2 traffic is the wall (marginal BW ~15.7TB/s); remaining 93us
//     fixed cost = serial staging @1 block/CU + 6144/block LDS conflicts
//     (2-way on every A-frag ds_read_b128: xor only covered row&7).
// R7: (a) chunked K staging: 3 chunks of 256 cols, double-buffered through
//     2x32KB LDS. Per step: issue next-chunk global loads -> 8 kk of MFMA on
//     current chunk -> vmcnt -> convert+ds_write -> barrier. Staging overlaps
//     compute; LDS 96->64KB. Pass B re-reads m from global (L3-resident).
//     (b) 1024-thr blocks, 16 waves, 1 col-tile x 4 row-frags per wave ->
//     acc=32 VGPR, target <=128 total -> 16 waves/CU (2x TLP of R6).
//     (c) swizzle xor widened to row&15 -> A-frag b128 reads conflict-free.

#define KTOT 768
#define ROWS 64
#define THREADS 1024
#define CHUNK 256                       // K cols per chunk
#define CHUNK_SHORTS (ROWS * CHUNK)     // 16384 shorts = 32 KB
#define TILE_SHORTS 12288               // 16-col fragment tile: 24kk*64lanes*8bf16

typedef __attribute__((ext_vector_type(8))) __bf16 bf16x8;
typedef __attribute__((ext_vector_type(8))) unsigned short ushort8;
typedef __attribute__((ext_vector_type(4))) float f32x4;

#define MFMA(a, b, c) __builtin_amdgcn_mfma_f32_16x16x32_bf16((a), (b), (c), 0, 0, 0)

__device__ __forceinline__ unsigned short f2bf(float f) {
    union { float f; unsigned u; } v; v.f = f;
    return (unsigned short)((v.u + 0x7FFFu + ((v.u >> 16) & 1u)) >> 16);  // RNE
}
__device__ __forceinline__ float bf2f(unsigned short b) {
    union { unsigned u; float f; } v; v.u = ((unsigned)b) << 16;
    return v.f;
}

// ---------------------------------------------------------------------------
// Pack weights -> bf16, fragment-major.
// For tile t (16 output cols), kk in [0,24), lane in [0,64):
//   chunk addr = ((t*24 + kk)*64 + lane)*8 shorts; p=lane&15, q=lane>>4:
//   element j = W[k = kk*32 + q*8 + j][n = t*16 + p].
// ---------------------------------------------------------------------------
__global__ void pack_weights(const float* __restrict__ wz, const float* __restrict__ uz,
                             const float* __restrict__ wr, const float* __restrict__ ur,
                             const float* __restrict__ w,  const float* __restrict__ u,
                             unsigned short* __restrict__ W1t, unsigned short* __restrict__ W2t)
{
    __shared__ unsigned short buf[KTOT * 16];   // [k][nl], 24 KB
    const int tid = threadIdx.x;
    const int b   = blockIdx.x;

    const float* Wsrc; const float* Usrc; int ncb; unsigned short* outp;
    if (b < 16)      { Wsrc = wz; Usrc = uz; ncb = b * 16;        outp = W1t + b * TILE_SHORTS; }
    else if (b < 32) { Wsrc = wr; Usrc = ur; ncb = (b - 16) * 16; outp = W1t + b * TILE_SHORTS; }
    else             { Wsrc = w;  Usrc = u;  ncb = (b - 32) * 16; outp = W2t + (b - 32) * TILE_SHORTS; }

    #pragma unroll
    for (int i = 0; i < 48; ++i) {
        int id = tid + i * 256;            // 768*16 elements
        int k = id >> 4, nl = id & 15;
        float v = (k < 512) ? Wsrc[k * 256 + ncb + nl]
                            : Usrc[(k - 512) * 256 + ncb + nl];
        buf[id] = f2bf(v);
    }
    __syncthreads();

    #pragma unroll
    for (int i = 0; i < 6; ++i) {
        int c = tid + i * 256;
        int kk = c >> 6, lane = c & 63;
        int p = lane & 15, q = lane >> 4;
        ushort8 pk;
        #pragma unroll
        for (int j = 0; j < 8; ++j)
            pk[j] = buf[(kk * 32 + q * 8 + j) * 16 + p];
        *(ushort8*)(outp + (unsigned)c * 8) = pk;
    }
}

// XOR-swizzled chunk index: 16B blocks permuted in groups of 16 by row&15.
// A-frag ds_read_b128 (16 rows, same k) -> 16 distinct 16B slots = 32 banks,
// conflict-free. Staging b64 writes (consecutive kblk, fixed row) also clean.
__device__ __forceinline__ int cidx(int row, int k) {   // k in [0, CHUNK)
    int kblk = k >> 3;
    int kb2 = (kblk & 16) | ((kblk ^ row) & 15);
    return row * CHUNK + kb2 * 8 + (k & 7);
}

__global__ __launch_bounds__(THREADS, 4) void fused_gru(
    const float* __restrict__ h_in,   // [BN,256]
    const float* __restrict__ msg,    // [BN,512]
    const float* __restrict__ mask,   // [BN]
    const unsigned short* __restrict__ W1t,  // 32 fragment tiles (z|r)
    const unsigned short* __restrict__ W2t,  // 16 fragment tiles
    float* __restrict__ out)          // [BN,256]
{
    __shared__ __align__(16) unsigned short B0[CHUNK_SHORTS];  // 32 KB
    __shared__ __align__(16) unsigned short B1[CHUNK_SHORTS];  // 32 KB
    __shared__ float maskS[ROWS];

    const int tid  = threadIdx.x;
    const int wave = tid >> 6;        // 0..15 -> col tile (cols wave*16..+16)
    const int lane = tid & 63;
    const int p    = lane & 15;
    const int q    = lane >> 4;
    const long r0  = (long)blockIdx.x * ROWS;

    // ---- staging helpers: issue (global->regs) / write (regs->LDS bf16) ----
    f32x4 st[4];
    auto stage_issue = [&](const float* base, int stride) {
        #pragma unroll
        for (int i = 0; i < 4; ++i) {
            int f = tid + i * THREADS;
            st[i] = *(const f32x4*)(base + (f >> 6) * stride + (f & 63) * 4);
        }
    };
    auto stage_write = [&](unsigned short* buf) {
        #pragma unroll
        for (int i = 0; i < 4; ++i) {
            int f = tid + i * THREADS;
            int row = f >> 6, c4 = f & 63;
            f32x4 v = st[i];
            unsigned long long pk =  (unsigned long long)f2bf(v.x)
                                  | ((unsigned long long)f2bf(v.y) << 16)
                                  | ((unsigned long long)f2bf(v.z) << 32)
                                  | ((unsigned long long)f2bf(v.w) << 48);
            *(unsigned long long*)&buf[cidx(row, c4 * 4)] = pk;
        }
    };

    // ---- prestage chunk c0 = m[:,0:256] ----
    stage_issue(msg + r0 * 512, 512);
    if (tid < ROWS) maskS[tid] = mask[r0 + tid];
    stage_write(B0);
    __syncthreads();

    // Wave owns fragment tile `wave` of each gate.
    const unsigned short* wzp = W1t + (long)wave * TILE_SHORTS + lane * 8;
    const unsigned short* wrp = wzp + 16L * TILE_SHORTS;
    const unsigned short* wbp = W2t + (long)wave * TILE_SHORTS + lane * 8;

    // ---- Z+R: 3 chunk-steps x 8 kk; weights depth-1 prefetched across steps ----
    f32x4 accz[4], accr[4];
    #pragma unroll
    for (int rt = 0; rt < 4; ++rt)
        #pragma unroll
        for (int i = 0; i < 4; ++i) { accz[rt][i] = 0.f; accr[rt][i] = 0.f; }

    bf16x8 zb = *(const bf16x8*)(wzp);
    bf16x8 rb = *(const bf16x8*)(wrp);

    auto zr_step = [&](const unsigned short* buf, int kk0) {
        #pragma unroll
        for (int kkl = 0; kkl < 8; ++kkl) {
            int kkg = kk0 + kkl;
            bf16x8 a[4];
            #pragma unroll
            for (int rt = 0; rt < 4; ++rt)
                a[rt] = *(const bf16x8*)&buf[cidx(rt * 16 + p, kkl * 32 + q * 8)];
            bf16x8 nzb, nrb;
            if (kkg < 23) {
                nzb = *(const bf16x8*)(wzp + (kkg + 1) * 512);
                nrb = *(const bf16x8*)(wrp + (kkg + 1) * 512);
            }
            __builtin_amdgcn_s_setprio(1);
            #pragma unroll
            for (int rt = 0; rt < 4; ++rt) accz[rt] = MFMA(a[rt], zb, accz[rt]);
            #pragma unroll
            for (int rt = 0; rt < 4; ++rt) accr[rt] = MFMA(a[rt], rb, accr[rt]);
            __builtin_amdgcn_s_setprio(0);
            if (kkg < 23) { zb = nzb; rb = nrb; }
        }
    };

    stage_issue(msg + r0 * 512 + 256, 512);   // c1 = m[:,256:512]
    zr_step(B0, 0);
    stage_write(B1);
    __syncthreads();

    stage_issue(h_in + r0 * 256, 256);        // c2 = h
    zr_step(B1, 8);
    stage_write(B0);
    __syncthreads();

    stage_issue(msg + r0 * 512, 512);         // pass-B m0 (re-read, L3-warm)
    zr_step(B0, 16);
    stage_write(B1);
    __syncthreads();

    // ---- sigmoid; cache h; overwrite h -> r*h in place (B0) ----
    float zs[4][4], rs[4][4], hs[4][4];
    #pragma unroll
    for (int rt = 0; rt < 4; ++rt)
        #pragma unroll
        for (int i = 0; i < 4; ++i) {
            zs[rt][i] = 1.f / (1.f + __expf(-accz[rt][i]));
            rs[rt][i] = 1.f / (1.f + __expf(-accr[rt][i]));
        }
    #pragma unroll
    for (int rt = 0; rt < 4; ++rt)
        #pragma unroll
        for (int i = 0; i < 4; ++i) {
            int row = rt * 16 + q * 4 + i;       // C/D: row = quad*4+reg
            int col = wave * 16 + p;             //      col = lane&15
            unsigned short* ptr = &B0[cidx(row, col)];
            float hv = bf2f(*ptr);
            hs[rt][i] = hv;
            *ptr = f2bf(rs[rt][i] * hv);
        }
    __syncthreads();

    // ---- Pass B: htil = tanh([rh | m0 | m1] @ W2t)  (K-order permuted) ----
    f32x4 acc[4];
    #pragma unroll
    for (int rt = 0; rt < 4; ++rt)
        #pragma unroll
        for (int i = 0; i < 4; ++i) acc[rt][i] = 0.f;

    bf16x8 bb = *(const bf16x8*)(wbp + 16 * 512);   // rh chunk = physical kk 16..23

    auto b_step = [&](const unsigned short* buf, int kk0, int nk0) {
        #pragma unroll
        for (int kkl = 0; kkl < 8; ++kkl) {
            int kkg = kk0 + kkl;
            bf16x8 a[4];
            #pragma unroll
            for (int rt = 0; rt < 4; ++rt)
                a[rt] = *(const bf16x8*)&buf[cidx(rt * 16 + p, kkl * 32 + q * 8)];
            int nk = (kkl < 7) ? (kkg + 1) : nk0;
            bf16x8 nbb;
            if (nk >= 0) nbb = *(const bf16x8*)(wbp + nk * 512);
            __builtin_amdgcn_s_setprio(1);
            #pragma unroll
            for (int rt = 0; rt < 4; ++rt) acc[rt] = MFMA(a[rt], bb, acc[rt]);
            __builtin_amdgcn_s_setprio(0);
            if (nk >= 0) bb = nbb;
        }
    };

    stage_issue(msg + r0 * 512 + 256, 512);   // m1 re-read
    b_step(B0, 16, 0);        // rh chunk (weights kk 16..23)
    __syncthreads();          // all waves done reading rh
    stage_write(B0);          // m1 -> B0
    b_step(B1, 0, 8);         // m0 chunk (weights kk 0..7)
    __syncthreads();          // m1 write visible
    b_step(B0, 8, -1);        // m1 chunk (weights kk 8..15)

    // ---- Fused epilogue ----
    #pragma unroll
    for (int rt = 0; rt < 4; ++rt)
        #pragma unroll
        for (int i = 0; i < 4; ++i) {
            int row  = rt * 16 + q * 4 + i;
            long grow = r0 + row;
            int col  = wave * 16 + p;
            float pre = acc[rt][i];
            float e  = __expf(-2.f * fabsf(pre));
            float t  = (1.f - e) / (1.f + e);
            float ht = (pre >= 0.f) ? t : -t;
            float zv = zs[rt][i];
            float hv = hs[rt][i];
            out[grow * 256 + col] = maskS[row] * (hv + zv * (ht - hv));
        }
}

extern "C" void kernel_launch(void* const* d_in, const int* in_sizes, int n_in,
                              void* d_out, int out_size, void* d_ws, size_t ws_size,
                              hipStream_t stream) {
    const float* h_in = (const float*)d_in[0];   // node_state [64,1024,256]
    const float* msg  = (const float*)d_in[1];   // message    [64,1024,512]
    const float* mask = (const float*)d_in[2];   // mask       [64,1024]
    const float* wz   = (const float*)d_in[3];
    const float* uz   = (const float*)d_in[4];
    const float* wr   = (const float*)d_in[5];
    const float* ur   = (const float*)d_in[6];
    const float* w    = (const float*)d_in[7];
    const float* u    = (const float*)d_in[8];

    unsigned short* W1t = (unsigned short*)d_ws;           // 32 tiles
    unsigned short* W2t = W1t + 32 * TILE_SHORTS;          // 16 tiles
    float* out = (float*)d_out;

    pack_weights<<<48, 256, 0, stream>>>(wz, uz, wr, ur, w, u, W1t, W2t);

    const int BN = 64 * 1024;
    fused_gru<<<BN / ROWS, THREADS, 0, stream>>>(h_in, msg, mask, W1t, W2t, out);
}